// Round 1
// baseline (634.666 us; speedup 1.0000x reference)
//
#include <hip/hip_runtime.h>

#define E_DIM 2048
#define S_LEN 2048
#define BATCH 2
#define NH 32
#define NG 8
#define HD 64
#define KV_DIM 512      // NG*HD
#define QKV_N 3072      // E + 2*KV
#define M_ROWS 4096     // B*S
#define SCALE_F 0.125f  // 1/sqrt(64)

typedef __bf16 bf16x8 __attribute__((ext_vector_type(8)));
typedef float f32x4 __attribute__((ext_vector_type(4)));

// ---------------- fp32 -> bf16 elementwise convert ----------------
__global__ void k_convert(const float* __restrict__ x, __bf16* __restrict__ xb, int n) {
    int i = (blockIdx.x * blockDim.x + threadIdx.x) * 4;
    if (i < n) {
        float4 v = *(const float4*)(x + i);
        xb[i + 0] = (__bf16)v.x;
        xb[i + 1] = (__bf16)v.y;
        xb[i + 2] = (__bf16)v.z;
        xb[i + 3] = (__bf16)v.w;
    }
}

// ---------------- W[K][N] fp32 -> Wt[N][K] bf16 (transpose+convert) ----------------
__global__ void k_transpose(const float* __restrict__ W, __bf16* __restrict__ Wt, int K, int N) {
    __shared__ float tile[32][33];
    int n0 = blockIdx.x * 32, k0 = blockIdx.y * 32;
    int tx = threadIdx.x, ty = threadIdx.y;
#pragma unroll
    for (int j = 0; j < 4; ++j)
        tile[ty + j * 8][tx] = W[(size_t)(k0 + ty + j * 8) * N + n0 + tx];
    __syncthreads();
#pragma unroll
    for (int j = 0; j < 4; ++j)
        Wt[(size_t)(n0 + ty + j * 8) * K + k0 + tx] = (__bf16)tile[tx][ty + j * 8];
}

// ---------------- bf16 MFMA GEMM: C[M][N] = A[M][K] @ Bt[N][K]^T ----------------
// OUT_F32 == 0: C is bf16.  OUT_F32 == 1: C is fp32, bias added.
template <int OUT_F32>
__global__ __launch_bounds__(256, 2)
void k_gemm_bt(const __bf16* __restrict__ A, const __bf16* __restrict__ Bt,
               void* __restrict__ Cout, const float* __restrict__ bias,
               int M, int N, int K) {
    __shared__ __attribute__((aligned(16))) __bf16 As[128][40];
    __shared__ __attribute__((aligned(16))) __bf16 Bs[128][40];
    const int t = threadIdx.x;
    const int lane = t & 63, wave = t >> 6;
    const int quad = lane >> 4, l16 = lane & 15;
    const int wr = wave >> 1, wc = wave & 1;
    const int m0 = blockIdx.y * 128, n0 = blockIdx.x * 128;
    const int srow = t >> 2, scol = (t & 3) * 8;

    f32x4 acc[4][4] = {};

    for (int k0 = 0; k0 < K; k0 += 32) {
        uint4 a0 = *(const uint4*)(A + (size_t)(m0 + srow) * K + k0 + scol);
        uint4 a1 = *(const uint4*)(A + (size_t)(m0 + 64 + srow) * K + k0 + scol);
        uint4 b0 = *(const uint4*)(Bt + (size_t)(n0 + srow) * K + k0 + scol);
        uint4 b1 = *(const uint4*)(Bt + (size_t)(n0 + 64 + srow) * K + k0 + scol);
        *(uint4*)&As[srow][scol] = a0;
        *(uint4*)&As[64 + srow][scol] = a1;
        *(uint4*)&Bs[srow][scol] = b0;
        *(uint4*)&Bs[64 + srow][scol] = b1;
        __syncthreads();
        bf16x8 af[4], bfr[4];
#pragma unroll
        for (int i = 0; i < 4; ++i) af[i] = *(const bf16x8*)&As[wr * 64 + i * 16 + l16][quad * 8];
#pragma unroll
        for (int j = 0; j < 4; ++j) bfr[j] = *(const bf16x8*)&Bs[wc * 64 + j * 16 + l16][quad * 8];
#pragma unroll
        for (int i = 0; i < 4; ++i)
#pragma unroll
            for (int j = 0; j < 4; ++j)
                acc[i][j] = __builtin_amdgcn_mfma_f32_16x16x32_bf16(af[i], bfr[j], acc[i][j], 0, 0, 0);
        __syncthreads();
    }

    // epilogue: C/D layout col=lane&15, row=quad*4+reg (verified m89/m91)
#pragma unroll
    for (int i = 0; i < 4; ++i) {
#pragma unroll
        for (int j = 0; j < 4; ++j) {
            const int row = m0 + wr * 64 + i * 16 + quad * 4;
            const int col = n0 + wc * 64 + j * 16 + l16;
#pragma unroll
            for (int r = 0; r < 4; ++r) {
                float v = acc[i][j][r];
                if (OUT_F32) {
                    ((float*)Cout)[(size_t)(row + r) * N + col] = v + bias[col];
                } else {
                    ((__bf16*)Cout)[(size_t)(row + r) * N + col] = (__bf16)v;
                }
            }
        }
    }
}

// ---------------- fused causal GQA flash attention ----------------
// grid: (S/64, NH, BATCH); block 256 (4 waves, each owns 16 query rows)
// qkv row layout: [q(0..2047) | k(2048..2559) | v(2560..3071)]
__global__ __launch_bounds__(256, 2)
void k_attn(const __bf16* __restrict__ qkv, __bf16* __restrict__ attnb) {
    const int q0 = blockIdx.x * 64;
    const int h = blockIdx.y;
    const int b = blockIdx.z;
    const int g = h >> 2;  // H/G = 4 consecutive query heads per KV head
    const int t = threadIdx.x;
    const int lane = t & 63, wave = t >> 6;
    const int quad = lane >> 4, l16 = lane & 15;

    __shared__ __attribute__((aligned(16))) __bf16 vT[64][40];     // [d][key], 32-key tile
    __shared__ __attribute__((aligned(16))) __bf16 pT[4][16][40];  // per-wave P: [q][key]

    const __bf16* base = qkv + (size_t)b * S_LEN * QKV_N;

    // Q A-fragments (A[m=lane&15][k=quad*8+j]), loaded once
    bf16x8 qf[2];
#pragma unroll
    for (int s = 0; s < 2; ++s)
        qf[s] = *(const bf16x8*)(base + (size_t)(q0 + wave * 16 + l16) * QKV_N + h * HD + s * 32 + quad * 8);

    f32x4 o_acc[4] = {};
    float m_state[4], l_state[4];
#pragma unroll
    for (int r = 0; r < 4; ++r) { m_state[r] = -__builtin_inff(); l_state[r] = 0.f; }

    const int ntiles = (q0 + 64) >> 5;  // causal: keys [0, q0+64)
    for (int it = 0; it < ntiles; ++it) {
        const int kv0 = it << 5;
        // cooperative V^T staging: thread t -> key = t&31, 8 d's
        {
            const int key = t & 31, dg = (t >> 5) << 3;
            uint4 vv = *(const uint4*)(base + (size_t)(kv0 + key) * QKV_N + (E_DIM + KV_DIM) + g * HD + dg);
            const __bf16* vs = (const __bf16*)&vv;
#pragma unroll
            for (int j = 0; j < 8; ++j) vT[dg + j][key] = vs[j];
        }
        __syncthreads();

        // scores: S = Q K^T over 2 key sub-tiles of 16
        f32x4 sc[2];
#pragma unroll
        for (int kt = 0; kt < 2; ++kt) {
            const __bf16* kp = base + (size_t)(kv0 + kt * 16 + l16) * QKV_N + E_DIM + g * HD;
            bf16x8 kf0 = *(const bf16x8*)(kp + quad * 8);
            bf16x8 kf1 = *(const bf16x8*)(kp + 32 + quad * 8);
            f32x4 z = {};
            z = __builtin_amdgcn_mfma_f32_16x16x32_bf16(qf[0], kf0, z, 0, 0, 0);
            z = __builtin_amdgcn_mfma_f32_16x16x32_bf16(qf[1], kf1, z, 0, 0, 0);
            sc[kt] = z;
        }

        // online softmax (row = quad*4+r lives in the quad's 16 lanes)
        float alpha4[4];
#pragma unroll
        for (int r = 0; r < 4; ++r) {
            const int qpos = q0 + wave * 16 + quad * 4 + r;
            float s0 = sc[0][r] * SCALE_F;
            float s1 = sc[1][r] * SCALE_F;
            if (kv0 + l16 > qpos) s0 = -__builtin_inff();
            if (kv0 + 16 + l16 > qpos) s1 = -__builtin_inff();
            float mx = fmaxf(s0, s1);
#pragma unroll
            for (int off = 8; off; off >>= 1) mx = fmaxf(mx, __shfl_xor(mx, off, 16));
            const float mn = fmaxf(m_state[r], mx);
            const float al = __expf(m_state[r] - mn);
            const float p0 = __expf(s0 - mn);
            const float p1 = __expf(s1 - mn);
            float rs = p0 + p1;
#pragma unroll
            for (int off = 8; off; off >>= 1) rs += __shfl_xor(rs, off, 16);
            m_state[r] = mn;
            l_state[r] = l_state[r] * al + rs;
            alpha4[r] = al;
            pT[wave][quad * 4 + r][l16] = (__bf16)p0;
            pT[wave][quad * 4 + r][16 + l16] = (__bf16)p1;
        }
        __syncthreads();

        // rescale O, then O += P @ V
#pragma unroll
        for (int nc = 0; nc < 4; ++nc) {
            f32x4 oo = o_acc[nc];
#pragma unroll
            for (int r = 0; r < 4; ++r) oo[r] *= alpha4[r];
            o_acc[nc] = oo;
        }
        bf16x8 pf = *(const bf16x8*)&pT[wave][l16][quad * 8];
#pragma unroll
        for (int nc = 0; nc < 4; ++nc) {
            bf16x8 vf = *(const bf16x8*)&vT[nc * 16 + l16][quad * 8];
            o_acc[nc] = __builtin_amdgcn_mfma_f32_16x16x32_bf16(pf, vf, o_acc[nc], 0, 0, 0);
        }
        __syncthreads();
    }

    // epilogue: write attn in [B,S,H*D] layout as bf16
#pragma unroll
    for (int nc = 0; nc < 4; ++nc) {
#pragma unroll
        for (int r = 0; r < 4; ++r) {
            const int row = b * S_LEN + q0 + wave * 16 + quad * 4 + r;
            const int col = h * HD + nc * 16 + l16;
            attnb[(size_t)row * E_DIM + col] = (__bf16)(o_acc[nc][r] / l_state[r]);
        }
    }
}

// ---------------- launch ----------------
extern "C" void kernel_launch(void* const* d_in, const int* in_sizes, int n_in,
                              void* d_out, int out_size, void* d_ws, size_t ws_size,
                              hipStream_t stream) {
    const float* x  = (const float*)d_in[0];
    const float* Wq = (const float*)d_in[1];
    const float* Wk = (const float*)d_in[2];
    const float* Wv = (const float*)d_in[3];
    const float* Wo = (const float*)d_in[4];
    const float* bo = (const float*)d_in[5];
    float* out = (float*)d_out;

    // workspace carve-up (all bf16):
    __bf16* xb    = (__bf16*)d_ws;                         // [4096][2048]
    __bf16* WtAll = xb + (size_t)M_ROWS * E_DIM;           // [3072][2048]  (Wq^T | Wk^T | Wv^T)
    __bf16* WoT   = WtAll + (size_t)QKV_N * E_DIM;         // [2048][2048]
    __bf16* qkv   = WoT + (size_t)E_DIM * E_DIM;           // [4096][3072]
    __bf16* attnb = qkv + (size_t)M_ROWS * QKV_N;          // [4096][2048]

    k_convert<<<(M_ROWS * E_DIM / 4 + 255) / 256, 256, 0, stream>>>(x, xb, M_ROWS * E_DIM);
    dim3 tb(32, 8);
    k_transpose<<<dim3(E_DIM / 32, E_DIM / 32), tb, 0, stream>>>(Wq, WtAll, E_DIM, E_DIM);
    k_transpose<<<dim3(KV_DIM / 32, E_DIM / 32), tb, 0, stream>>>(Wk, WtAll + (size_t)E_DIM * E_DIM, E_DIM, KV_DIM);
    k_transpose<<<dim3(KV_DIM / 32, E_DIM / 32), tb, 0, stream>>>(Wv, WtAll + (size_t)(E_DIM + KV_DIM) * E_DIM, E_DIM, KV_DIM);
    k_transpose<<<dim3(E_DIM / 32, E_DIM / 32), tb, 0, stream>>>(Wo, WoT, E_DIM, E_DIM);

    // fused QKV projection: [4096,3072] = xb @ [Wq|Wk|Wv]
    k_gemm_bt<0><<<dim3(QKV_N / 128, M_ROWS / 128), 256, 0, stream>>>(
        xb, WtAll, (void*)qkv, nullptr, M_ROWS, QKV_N, E_DIM);

    // fused causal GQA attention
    k_attn<<<dim3(S_LEN / 64, NH, BATCH), 256, 0, stream>>>(qkv, attnb);

    // output projection + bias (fp32 out)
    k_gemm_bt<1><<<dim3(E_DIM / 128, M_ROWS / 128), 256, 0, stream>>>(
        attnb, WoT, d_out, bo, M_ROWS, E_DIM, E_DIM);
}

// Round 2
// 538.732 us; speedup vs baseline: 1.1781x; 1.1781x over previous
//
#include <hip/hip_runtime.h>

#define E_DIM 2048
#define S_LEN 2048
#define NH 32
#define HD 64
#define KV_DIM 512
#define QKV_N 3072      // E + 2*KV
#define M_ROWS 4096     // B*S
#define QK_SCALE 0.18033688011112042f  // (1/sqrt(64)) * log2(e)

typedef __bf16 bf16x8 __attribute__((ext_vector_type(8)));
typedef float f32x4 __attribute__((ext_vector_type(4)));

__device__ __forceinline__ void async_lds16(const __bf16* g, __bf16* l) {
    __builtin_amdgcn_global_load_lds(
        (const __attribute__((address_space(1))) void*)g,
        (__attribute__((address_space(3))) void*)l, 16, 0, 0);
}

// ---------------- fp32 -> bf16 elementwise convert ----------------
__global__ void k_convert(const float* __restrict__ x, __bf16* __restrict__ xb, int n) {
    int i = (blockIdx.x * blockDim.x + threadIdx.x) * 4;
    if (i < n) {
        float4 v = *(const float4*)(x + i);
        xb[i + 0] = (__bf16)v.x;
        xb[i + 1] = (__bf16)v.y;
        xb[i + 2] = (__bf16)v.z;
        xb[i + 3] = (__bf16)v.w;
    }
}

// ---------------- W[K][N] fp32 -> Wt[N][K] bf16 (transpose+convert+scale) ----------------
__global__ void k_transpose(const float* __restrict__ W, __bf16* __restrict__ Wt, int K, int N,
                            float scale) {
    __shared__ float tile[32][33];
    int n0 = blockIdx.x * 32, k0 = blockIdx.y * 32;
    int tx = threadIdx.x, ty = threadIdx.y;
#pragma unroll
    for (int j = 0; j < 4; ++j)
        tile[ty + j * 8][tx] = W[(size_t)(k0 + ty + j * 8) * N + n0 + tx];
    __syncthreads();
#pragma unroll
    for (int j = 0; j < 4; ++j)
        Wt[(size_t)(n0 + ty + j * 8) * K + k0 + tx] = (__bf16)(tile[tx][ty + j * 8] * scale);
}

// ---------------- bf16 MFMA GEMM (m97-style global_load_lds staging, swizzled LDS) ----------
// C[M][N] = A[M][K] @ Bt[N][K]^T.  OUT_F32==1: fp32 out + bias.
template <int OUT_F32>
__global__ __launch_bounds__(256, 2)
void k_gemm_bt(const __bf16* __restrict__ A, const __bf16* __restrict__ Bt,
               void* __restrict__ Cout, const float* __restrict__ bias,
               int M, int N, int K) {
    __shared__ __attribute__((aligned(16))) __bf16 As[128 * 32];
    __shared__ __attribute__((aligned(16))) __bf16 Bs[128 * 32];
    const int t = threadIdx.x;
    const int lane = t & 63, wave = t >> 6;
    const int quad = lane >> 4, l16 = lane & 15;
    const int wr = wave >> 1, wc = wave & 1;
    const int m0 = blockIdx.y * 128, n0 = blockIdx.x * 128;

    // staging map: 16B chunk c -> LDS block c; content = row (c>>2), col-block ((c&3)^s(row))
    const int srow = t >> 2;
    const int sblk = (t & 3) ^ ((t >> 3) & 3);
    const __bf16* gA0 = A + (size_t)(m0 + srow) * K + sblk * 8;
    const __bf16* gA1 = gA0 + (size_t)64 * K;
    const __bf16* gB0 = Bt + (size_t)(n0 + srow) * K + sblk * 8;
    const __bf16* gB1 = gB0 + (size_t)64 * K;
    __bf16* lA0 = As + wave * 512;          // bytes: wave*1024
    __bf16* lA1 = As + 2048 + wave * 512;   // second 4KB half
    __bf16* lB0 = Bs + wave * 512;
    __bf16* lB1 = Bs + 2048 + wave * 512;

    f32x4 acc[4][4] = {};

    for (int k0 = 0; k0 < K; k0 += 32) {
        async_lds16(gA0 + k0, lA0);
        async_lds16(gA1 + k0, lA1);
        async_lds16(gB0 + k0, lB0);
        async_lds16(gB1 + k0, lB1);
        __syncthreads();
        bf16x8 af[4], bfr[4];
#pragma unroll
        for (int i = 0; i < 4; ++i) {
            const int row = wr * 64 + i * 16 + l16;
            af[i] = *(const bf16x8*)((const char*)As + row * 64 + ((quad ^ ((row >> 1) & 3)) * 16));
        }
#pragma unroll
        for (int j = 0; j < 4; ++j) {
            const int row = wc * 64 + j * 16 + l16;
            bfr[j] = *(const bf16x8*)((const char*)Bs + row * 64 + ((quad ^ ((row >> 1) & 3)) * 16));
        }
#pragma unroll
        for (int i = 0; i < 4; ++i)
#pragma unroll
            for (int j = 0; j < 4; ++j)
                acc[i][j] = __builtin_amdgcn_mfma_f32_16x16x32_bf16(af[i], bfr[j], acc[i][j], 0, 0, 0);
        __syncthreads();
    }

#pragma unroll
    for (int i = 0; i < 4; ++i)
#pragma unroll
        for (int j = 0; j < 4; ++j) {
            const int row = m0 + wr * 64 + i * 16 + quad * 4;
            const int col = n0 + wc * 64 + j * 16 + l16;
#pragma unroll
            for (int r = 0; r < 4; ++r) {
                float v = acc[i][j][r];
                if (OUT_F32) ((float*)Cout)[(size_t)(row + r) * N + col] = v + bias[col];
                else ((__bf16*)Cout)[(size_t)(row + r) * N + col] = (__bf16)v;
            }
        }
}

// ---------------- fused causal GQA flash attention (S^T formulation) ----------------
// grid: (S/64, NH, B); 4 waves. Wave owns 16 queries; lane owns ONE query (l16).
// 128-key KV tiles; scores computed as S^T = K·Q^T so softmax is per-lane + 2 shuffles.
__global__ __launch_bounds__(256, 4)
void k_attn(const __bf16* __restrict__ qkv, __bf16* __restrict__ attnb) {
    const int q0 = blockIdx.x * 64;
    const int h = blockIdx.y, b = blockIdx.z, g = h >> 2;
    const int t = threadIdx.x;
    const int lane = t & 63, wave = t >> 6;
    const int quad = lane >> 4, l16 = lane & 15;

    __shared__ __attribute__((aligned(16))) __bf16 vT[64][136];   // [d][key], 128-key tile
    __shared__ __attribute__((aligned(16))) __bf16 pT[4][2048];   // per-wave P^T, 16 q x 256B, swizzled

    const __bf16* base = qkv + (size_t)b * S_LEN * QKV_N;
    const int qrow = q0 + wave * 16 + l16;

    // Q fragments (B-operand: n=q=l16, k=d=quad*8+j)
    bf16x8 qf0 = *(const bf16x8*)(base + (size_t)qrow * QKV_N + h * HD + quad * 8);
    bf16x8 qf1 = *(const bf16x8*)(base + (size_t)qrow * QKV_N + h * HD + 32 + quad * 8);

    f32x4 o0 = {}, o1 = {}, o2 = {}, o3 = {};
    float m_st = -__builtin_inff(), l_st = 0.f;

    // V staging: wave w stages d-slice [16w,16w+16) for keys {2*lane, 2*lane+1}
    const int vkey = lane * 2;
    const int vdg = wave * 16;
    const __bf16* vsrc = base + (E_DIM + KV_DIM) + g * HD + vdg;

    const int ntiles = (q0 + 191) >> 7;
    for (int it = 0; it < ntiles; ++it) {
        const int kv0 = it << 7;
        // ---- stage V^T (packed u32 writes: 2 keys per word) ----
        {
            const __bf16* p0 = vsrc + (size_t)(kv0 + vkey) * QKV_N;
            union { uint4 q; unsigned short s[8]; } a0, a1, b0, b1;
            a0.q = *(const uint4*)(p0);
            a1.q = *(const uint4*)(p0 + 8);
            b0.q = *(const uint4*)(p0 + QKV_N);
            b1.q = *(const uint4*)(p0 + QKV_N + 8);
#pragma unroll
            for (int j = 0; j < 8; ++j) {
                *(uint32_t*)&vT[vdg + j][vkey]     = (uint32_t)a0.s[j] | ((uint32_t)b0.s[j] << 16);
                *(uint32_t*)&vT[vdg + 8 + j][vkey] = (uint32_t)a1.s[j] | ((uint32_t)b1.s[j] << 16);
            }
        }
        // ---- S^T = K·Q^T: A=K (m=key), B=Q (n=q); 8 tiles of 16 keys ----
        f32x4 sc[8];
#pragma unroll
        for (int kt = 0; kt < 8; ++kt) {
            const __bf16* kp = base + (size_t)(kv0 + kt * 16 + l16) * QKV_N + E_DIM + g * HD;
            bf16x8 kf0 = *(const bf16x8*)(kp + quad * 8);
            bf16x8 kf1 = *(const bf16x8*)(kp + 32 + quad * 8);
            f32x4 z = {};
            z = __builtin_amdgcn_mfma_f32_16x16x32_bf16(kf0, qf0, z, 0, 0, 0);
            z = __builtin_amdgcn_mfma_f32_16x16x32_bf16(kf1, qf1, z, 0, 0, 0);
            sc[kt] = z;
        }
        // causal mask: only the last (diagonal) tile needs it
        if (it == ntiles - 1) {
#pragma unroll
            for (int kt = 0; kt < 8; ++kt)
#pragma unroll
                for (int r = 0; r < 4; ++r)
                    if (kv0 + kt * 16 + quad * 4 + r > qrow) sc[kt][r] = -__builtin_inff();
        }
        // ---- online softmax, exp2 domain (scale folded into Wq) ----
        float mx = -__builtin_inff();
#pragma unroll
        for (int kt = 0; kt < 8; ++kt)
#pragma unroll
            for (int r = 0; r < 4; ++r) mx = fmaxf(mx, sc[kt][r]);
        mx = fmaxf(mx, __shfl_xor(mx, 16));
        mx = fmaxf(mx, __shfl_xor(mx, 32));
        const float mn = fmaxf(m_st, mx);
        const float al = exp2f(m_st - mn);
        float rs = 0.f;
#pragma unroll
        for (int kt = 0; kt < 8; ++kt) {
            f32x4 s4 = sc[kt];
#pragma unroll
            for (int r = 0; r < 4; ++r) { s4[r] = exp2f(s4[r] - mn); rs += s4[r]; }
            sc[kt] = s4;
        }
        rs += __shfl_xor(rs, 16);
        rs += __shfl_xor(rs, 32);
        m_st = mn;
        l_st = l_st * al + rs;
#pragma unroll
        for (int r = 0; r < 4; ++r) { o0[r] *= al; o1[r] *= al; o2[r] *= al; o3[r] *= al; }
        // ---- P^T -> per-wave LDS: lane writes 4 consecutive keys (8B), XOR-16B swizzle ----
#pragma unroll
        for (int kt = 0; kt < 8; ++kt) {
            __bf16 pb[4];
#pragma unroll
            for (int r = 0; r < 4; ++r) pb[r] = (__bf16)sc[kt][r];
            const int blk = (kt * 2 + (quad >> 1)) ^ l16;
            char* dst = (char*)&pT[wave][0] + l16 * 256 + blk * 16 + (quad & 1) * 8;
            *(uint2*)dst = *(const uint2*)pb;
        }
        __syncthreads();   // vT staged & visible (P is per-wave, ordered by lgkmcnt)
        // ---- O^T += V^T · P^T  (A=V^T m=d, B=P^T n=q) ----
#pragma unroll
        for (int c = 0; c < 4; ++c) {
            const char* psrc = (const char*)&pT[wave][0] + l16 * 256 + (((c * 4 + quad) ^ l16) * 16);
            bf16x8 pf = *(const bf16x8*)psrc;
            bf16x8 vf0 = *(const bf16x8*)&vT[l16][c * 32 + quad * 8];
            bf16x8 vf1 = *(const bf16x8*)&vT[16 + l16][c * 32 + quad * 8];
            bf16x8 vf2 = *(const bf16x8*)&vT[32 + l16][c * 32 + quad * 8];
            bf16x8 vf3 = *(const bf16x8*)&vT[48 + l16][c * 32 + quad * 8];
            o0 = __builtin_amdgcn_mfma_f32_16x16x32_bf16(vf0, pf, o0, 0, 0, 0);
            o1 = __builtin_amdgcn_mfma_f32_16x16x32_bf16(vf1, pf, o1, 0, 0, 0);
            o2 = __builtin_amdgcn_mfma_f32_16x16x32_bf16(vf2, pf, o2, 0, 0, 0);
            o3 = __builtin_amdgcn_mfma_f32_16x16x32_bf16(vf3, pf, o3, 0, 0, 0);
        }
        __syncthreads();   // PV reads done before next tile's staging
    }

    // ---- epilogue: O^T lane layout col=q=l16, row=d=quad*4+r; pack 4 bf16 per store ----
    const float inv = 1.f / l_st;
    __bf16* orow = attnb + (size_t)(b * S_LEN + qrow) * E_DIM + h * HD + quad * 4;
    f32x4 oo[4] = {o0, o1, o2, o3};
#pragma unroll
    for (int dt = 0; dt < 4; ++dt) {
        __bf16 ob[4];
#pragma unroll
        for (int r = 0; r < 4; ++r) ob[r] = (__bf16)(oo[dt][r] * inv);
        *(uint2*)(orow + dt * 16) = *(const uint2*)ob;
    }
}

// ---------------- launch ----------------
extern "C" void kernel_launch(void* const* d_in, const int* in_sizes, int n_in,
                              void* d_out, int out_size, void* d_ws, size_t ws_size,
                              hipStream_t stream) {
    const float* x  = (const float*)d_in[0];
    const float* Wq = (const float*)d_in[1];
    const float* Wk = (const float*)d_in[2];
    const float* Wv = (const float*)d_in[3];
    const float* Wo = (const float*)d_in[4];
    const float* bo = (const float*)d_in[5];

    __bf16* xb    = (__bf16*)d_ws;                         // [4096][2048]
    __bf16* WtAll = xb + (size_t)M_ROWS * E_DIM;           // [3072][2048]
    __bf16* WoT   = WtAll + (size_t)QKV_N * E_DIM;         // [2048][2048]
    __bf16* qkv   = WoT + (size_t)E_DIM * E_DIM;           // [4096][3072]
    __bf16* attnb = qkv + (size_t)M_ROWS * QKV_N;          // [4096][2048]

    k_convert<<<(M_ROWS * E_DIM / 4 + 255) / 256, 256, 0, stream>>>(x, xb, M_ROWS * E_DIM);
    dim3 tb(32, 8);
    // fold softmax scale * log2(e) into Wq so attention works in exp2 domain
    k_transpose<<<dim3(E_DIM / 32, E_DIM / 32), tb, 0, stream>>>(Wq, WtAll, E_DIM, E_DIM, QK_SCALE);
    k_transpose<<<dim3(KV_DIM / 32, E_DIM / 32), tb, 0, stream>>>(Wk, WtAll + (size_t)E_DIM * E_DIM, E_DIM, KV_DIM, 1.0f);
    k_transpose<<<dim3(KV_DIM / 32, E_DIM / 32), tb, 0, stream>>>(Wv, WtAll + (size_t)(E_DIM + KV_DIM) * E_DIM, E_DIM, KV_DIM, 1.0f);
    k_transpose<<<dim3(E_DIM / 32, E_DIM / 32), tb, 0, stream>>>(Wo, WoT, E_DIM, E_DIM, 1.0f);

    // fused QKV projection
    k_gemm_bt<0><<<dim3(QKV_N / 128, M_ROWS / 128), 256, 0, stream>>>(
        xb, WtAll, (void*)qkv, nullptr, M_ROWS, QKV_N, E_DIM);

    // fused causal GQA attention
    k_attn<<<dim3(S_LEN / 64, NH, 2), 256, 0, stream>>>(qkv, attnb);

    // output projection + bias
    k_gemm_bt<1><<<dim3(E_DIM / 128, M_ROWS / 128), 256, 0, stream>>>(
        attnb, WoT, d_out, bo, M_ROWS, E_DIM, E_DIM);
}

// Round 3
// 473.866 us; speedup vs baseline: 1.3393x; 1.1369x over previous
//
#include <hip/hip_runtime.h>

#define E_DIM 2048
#define S_LEN 2048
#define NH 32
#define HD 64
#define KV_DIM 512
#define QKV_N 3072      // E + 2*KV
#define M_ROWS 4096     // B*S
#define QK_SCALE 0.18033688011112042f  // (1/sqrt(64)) * log2(e)

typedef __bf16 bf16x8 __attribute__((ext_vector_type(8)));
typedef float f32x4 __attribute__((ext_vector_type(4)));

__device__ __forceinline__ void async_lds16(const __bf16* g, __bf16* l) {
    __builtin_amdgcn_global_load_lds(
        (const __attribute__((address_space(1))) void*)g,
        (__attribute__((address_space(3))) void*)l, 16, 0, 0);
}

// ---------------- fp32 -> bf16 elementwise convert ----------------
__global__ void k_convert(const float* __restrict__ x, __bf16* __restrict__ xb, int n) {
    int i = (blockIdx.x * blockDim.x + threadIdx.x) * 4;
    if (i < n) {
        float4 v = *(const float4*)(x + i);
        xb[i + 0] = (__bf16)v.x;
        xb[i + 1] = (__bf16)v.y;
        xb[i + 2] = (__bf16)v.z;
        xb[i + 3] = (__bf16)v.w;
    }
}

// ---------------- W[K][N] fp32 -> Wt[N][K] bf16 (transpose+convert+scale) ----------------
__global__ void k_transpose(const float* __restrict__ W, __bf16* __restrict__ Wt, int K, int N,
                            float scale) {
    __shared__ float tile[32][33];
    int n0 = blockIdx.x * 32, k0 = blockIdx.y * 32;
    int tx = threadIdx.x, ty = threadIdx.y;
#pragma unroll
    for (int j = 0; j < 4; ++j)
        tile[ty + j * 8][tx] = W[(size_t)(k0 + ty + j * 8) * N + n0 + tx];
    __syncthreads();
#pragma unroll
    for (int j = 0; j < 4; ++j)
        Wt[(size_t)(n0 + ty + j * 8) * K + k0 + tx] = (__bf16)(tile[tx][ty + j * 8] * scale);
}

// ---------------- bf16 MFMA GEMM, BK=64 per barrier round ----------------
// C[M][N] = A[M][K] @ Bt[N][K]^T.  OUT_F32==1: fp32 out + bias.
template <int OUT_F32>
__global__ __launch_bounds__(256, 2)
void k_gemm_bt(const __bf16* __restrict__ A, const __bf16* __restrict__ Bt,
               void* __restrict__ Cout, const float* __restrict__ bias,
               int M, int N, int K) {
    __shared__ __attribute__((aligned(16))) __bf16 As[128 * 64];
    __shared__ __attribute__((aligned(16))) __bf16 Bs[128 * 64];
    const int t = threadIdx.x;
    const int lane = t & 63, wave = t >> 6;
    const int quad = lane >> 4, l16 = lane & 15;
    const int wr = wave >> 1, wc = wave & 1;
    const int m0 = blockIdx.y * 128, n0 = blockIdx.x * 128;

    const int srow = t >> 2;
    const int sblk = (t & 3) ^ ((t >> 3) & 3);
    const __bf16* gA0 = A + (size_t)(m0 + srow) * K + sblk * 8;
    const __bf16* gA1 = gA0 + (size_t)64 * K;
    const __bf16* gB0 = Bt + (size_t)(n0 + srow) * K + sblk * 8;
    const __bf16* gB1 = gB0 + (size_t)64 * K;

    f32x4 acc[4][4] = {};

    for (int k0 = 0; k0 < K; k0 += 64) {
#pragma unroll
        for (int ks = 0; ks < 2; ++ks) {
            async_lds16(gA0 + k0 + ks * 32, As + ks * 4096 + wave * 512);
            async_lds16(gA1 + k0 + ks * 32, As + ks * 4096 + 2048 + wave * 512);
            async_lds16(gB0 + k0 + ks * 32, Bs + ks * 4096 + wave * 512);
            async_lds16(gB1 + k0 + ks * 32, Bs + ks * 4096 + 2048 + wave * 512);
        }
        __syncthreads();
#pragma unroll
        for (int ks = 0; ks < 2; ++ks) {
            bf16x8 af[4], bfr[4];
#pragma unroll
            for (int i = 0; i < 4; ++i) {
                const int row = wr * 64 + i * 16 + l16;
                af[i] = *(const bf16x8*)((const char*)As + ks * 8192 + row * 64 +
                                         ((quad ^ ((row >> 1) & 3)) * 16));
            }
#pragma unroll
            for (int j = 0; j < 4; ++j) {
                const int row = wc * 64 + j * 16 + l16;
                bfr[j] = *(const bf16x8*)((const char*)Bs + ks * 8192 + row * 64 +
                                          ((quad ^ ((row >> 1) & 3)) * 16));
            }
#pragma unroll
            for (int i = 0; i < 4; ++i)
#pragma unroll
                for (int j = 0; j < 4; ++j)
                    acc[i][j] = __builtin_amdgcn_mfma_f32_16x16x32_bf16(af[i], bfr[j], acc[i][j], 0, 0, 0);
        }
        __syncthreads();
    }

#pragma unroll
    for (int i = 0; i < 4; ++i)
#pragma unroll
        for (int j = 0; j < 4; ++j) {
            const int row = m0 + wr * 64 + i * 16 + quad * 4;
            const int col = n0 + wc * 64 + j * 16 + l16;
#pragma unroll
            for (int r = 0; r < 4; ++r) {
                float v = acc[i][j][r];
                if (OUT_F32) ((float*)Cout)[(size_t)(row + r) * N + col] = v + bias[col];
                else ((__bf16*)Cout)[(size_t)(row + r) * N + col] = (__bf16)v;
            }
        }
}

// ---------------- fused causal GQA flash attention, 2 heads per wave ----------------
// grid: (S/64, 16 head-pairs, B); 4 waves; wave owns 16 queries (lane l16 = one query)
// for 2 consecutive heads of one KV group. 128-key macro tiles (V staged once),
// two 64-key micro tiles (score regs stay small). Longest blocks launch first.
__global__ __launch_bounds__(256, 4)
void k_attn(const __bf16* __restrict__ qkv, __bf16* __restrict__ attnb) {
    const int q0 = (int)(gridDim.x - 1 - blockIdx.x) * 64;   // reversed: long blocks first
    const int gp = blockIdx.y;
    const int g = gp >> 1;
    const int h0 = g * 4 + (gp & 1) * 2;   // heads h0, h0+1 (same KV group g)
    const int b = blockIdx.z;
    const int t = threadIdx.x;
    const int lane = t & 63, wave = t >> 6;
    const int quad = lane >> 4, l16 = lane & 15;

    __shared__ __attribute__((aligned(16))) __bf16 vT[64][136];   // [d][key 0..127]
    __shared__ __attribute__((aligned(16))) __bf16 pT[4][2][1024]; // [wave][head][16q x 64k] swizzled

    const __bf16* base = qkv + (size_t)b * S_LEN * QKV_N;
    const int qrow = q0 + wave * 16 + l16;

    bf16x8 qf[2][2];
#pragma unroll
    for (int h = 0; h < 2; ++h)
#pragma unroll
        for (int s = 0; s < 2; ++s)
            qf[h][s] = *(const bf16x8*)(base + (size_t)qrow * QKV_N + (h0 + h) * HD + s * 32 + quad * 8);

    f32x4 o[2][4] = {};
    float m_st[2], l_st[2];
    m_st[0] = m_st[1] = -__builtin_inff();
    l_st[0] = l_st[1] = 0.f;

    const int vkey = lane * 2, vdg = wave * 16;
    const __bf16* vsrc = base + (E_DIM + KV_DIM) + g * HD + vdg;
    const __bf16* ksrc = base + E_DIM + g * HD;
    const int kend = q0 + 64;
    const int nmac = (kend + 127) >> 7;

    // QK for one 64-key micro tile, both heads (K fragments shared)
    auto qk = [&](int kb, f32x4* sA, f32x4* sB) {
#pragma unroll
        for (int kt = 0; kt < 4; ++kt) {
            const __bf16* kp = ksrc + (size_t)(kb + kt * 16 + l16) * QKV_N;
            bf16x8 kf0 = *(const bf16x8*)(kp + quad * 8);
            bf16x8 kf1 = *(const bf16x8*)(kp + 32 + quad * 8);
            f32x4 z = {};
            z = __builtin_amdgcn_mfma_f32_16x16x32_bf16(kf0, qf[0][0], z, 0, 0, 0);
            sA[kt] = __builtin_amdgcn_mfma_f32_16x16x32_bf16(kf1, qf[0][1], z, 0, 0, 0);
            f32x4 w = {};
            w = __builtin_amdgcn_mfma_f32_16x16x32_bf16(kf0, qf[1][0], w, 0, 0, 0);
            sB[kt] = __builtin_amdgcn_mfma_f32_16x16x32_bf16(kf1, qf[1][1], w, 0, 0, 0);
        }
    };

    // mask + online softmax (tree reductions) + P write, one head
    auto softmax_p = [&](int kb, int h, f32x4* sc) {
        if (kb == q0) {  // diagonal micro tile
#pragma unroll
            for (int kt = 0; kt < 4; ++kt) {
                const int kbase = kb + kt * 16 + quad * 4;
#pragma unroll
                for (int r = 0; r < 4; ++r)
                    if (kbase + r > qrow) sc[kt][r] = -__builtin_inff();
            }
        }
        f32x4 m4;
#pragma unroll
        for (int r = 0; r < 4; ++r)
            m4[r] = fmaxf(fmaxf(sc[0][r], sc[1][r]), fmaxf(sc[2][r], sc[3][r]));
        float mx = fmaxf(fmaxf(m4[0], m4[1]), fmaxf(m4[2], m4[3]));
        mx = fmaxf(mx, __shfl_xor(mx, 16));
        mx = fmaxf(mx, __shfl_xor(mx, 32));
        const float mn = fmaxf(m_st[h], mx);
        const float al = exp2f(m_st[h] - mn);
#pragma unroll
        for (int kt = 0; kt < 4; ++kt)
#pragma unroll
            for (int r = 0; r < 4; ++r) sc[kt][r] = exp2f(sc[kt][r] - mn);
        f32x4 s4;
#pragma unroll
        for (int r = 0; r < 4; ++r)
            s4[r] = (sc[0][r] + sc[1][r]) + (sc[2][r] + sc[3][r]);
        float rs = (s4[0] + s4[1]) + (s4[2] + s4[3]);
        rs += __shfl_xor(rs, 16);
        rs += __shfl_xor(rs, 32);
        m_st[h] = mn;
        l_st[h] = l_st[h] * al + rs;
#pragma unroll
        for (int c = 0; c < 4; ++c)
#pragma unroll
            for (int r = 0; r < 4; ++r) o[h][c][r] *= al;
        char* prow = (char*)&pT[wave][h][0] + l16 * 128;
#pragma unroll
        for (int kt = 0; kt < 4; ++kt) {
            __bf16 pb[4];
#pragma unroll
            for (int r = 0; r < 4; ++r) pb[r] = (__bf16)sc[kt][r];
            *(uint2*)(prow + ((2 * kt + (quad >> 1)) ^ (l16 & 7)) * 16 + (quad & 1) * 8) =
                *(const uint2*)pb;
        }
    };

    // O^T += V^T · P^T for micro tile m, both heads (V fragments shared)
    auto pv = [&](int m) {
        bf16x8 vf[4][2];
        const int koff = m * 64;
#pragma unroll
        for (int c = 0; c < 4; ++c)
#pragma unroll
            for (int kh = 0; kh < 2; ++kh)
                vf[c][kh] = *(const bf16x8*)&vT[c * 16 + l16][koff + kh * 32 + quad * 8];
#pragma unroll
        for (int h = 0; h < 2; ++h) {
            const char* prow = (const char*)&pT[wave][h][0] + l16 * 128;
            bf16x8 pf0 = *(const bf16x8*)(prow + ((0 + quad) ^ (l16 & 7)) * 16);
            bf16x8 pf1 = *(const bf16x8*)(prow + ((4 + quad) ^ (l16 & 7)) * 16);
#pragma unroll
            for (int c = 0; c < 4; ++c) {
                o[h][c] = __builtin_amdgcn_mfma_f32_16x16x32_bf16(vf[c][0], pf0, o[h][c], 0, 0, 0);
                o[h][c] = __builtin_amdgcn_mfma_f32_16x16x32_bf16(vf[c][1], pf1, o[h][c], 0, 0, 0);
            }
        }
    };

    for (int it = 0; it < nmac; ++it) {
        const int kv0 = it << 7;
        // V global loads issued early; packed after QK so latency hides under MFMA
        const __bf16* vp = vsrc + (size_t)(kv0 + vkey) * QKV_N;
        uint4 va0 = *(const uint4*)(vp);
        uint4 va1 = *(const uint4*)(vp + 8);
        uint4 vb0 = *(const uint4*)(vp + QKV_N);
        uint4 vb1 = *(const uint4*)(vp + QKV_N + 8);

        f32x4 scA[4], scB[4];
        qk(kv0, scA, scB);

        {   // pack V^T into LDS (2 keys per u32)
            const unsigned short* a0 = (const unsigned short*)&va0;
            const unsigned short* a1 = (const unsigned short*)&va1;
            const unsigned short* b0 = (const unsigned short*)&vb0;
            const unsigned short* b1 = (const unsigned short*)&vb1;
#pragma unroll
            for (int j = 0; j < 8; ++j) {
                *(uint32_t*)&vT[vdg + j][vkey] = (uint32_t)a0[j] | ((uint32_t)b0[j] << 16);
                *(uint32_t*)&vT[vdg + 8 + j][vkey] = (uint32_t)a1[j] | ((uint32_t)b1[j] << 16);
            }
        }
        softmax_p(kv0, 0, scA);
        softmax_p(kv0, 1, scB);
        __syncthreads();          // vT visible to all waves
        pv(0);

        const int kb1 = kv0 + 64;
        if (kb1 < kend) {         // second micro tile (skipped when fully masked)
            qk(kb1, scA, scB);
            softmax_p(kb1, 0, scA);
            softmax_p(kb1, 1, scB);
            pv(1);
        }
        __syncthreads();          // all vT reads done before next macro's staging
    }

#pragma unroll
    for (int h = 0; h < 2; ++h) {
        const float inv = 1.f / l_st[h];
        __bf16* orow = attnb + (size_t)(b * S_LEN + qrow) * E_DIM + (h0 + h) * HD + quad * 4;
#pragma unroll
        for (int dt = 0; dt < 4; ++dt) {
            __bf16 ob[4];
#pragma unroll
            for (int r = 0; r < 4; ++r) ob[r] = (__bf16)(o[h][dt][r] * inv);
            *(uint2*)(orow + dt * 16) = *(const uint2*)ob;
        }
    }
}

// ---------------- launch ----------------
extern "C" void kernel_launch(void* const* d_in, const int* in_sizes, int n_in,
                              void* d_out, int out_size, void* d_ws, size_t ws_size,
                              hipStream_t stream) {
    const float* x  = (const float*)d_in[0];
    const float* Wq = (const float*)d_in[1];
    const float* Wk = (const float*)d_in[2];
    const float* Wv = (const float*)d_in[3];
    const float* Wo = (const float*)d_in[4];
    const float* bo = (const float*)d_in[5];

    __bf16* xb    = (__bf16*)d_ws;                         // [4096][2048]
    __bf16* WtAll = xb + (size_t)M_ROWS * E_DIM;           // [3072][2048]
    __bf16* WoT   = WtAll + (size_t)QKV_N * E_DIM;         // [2048][2048]
    __bf16* qkv   = WoT + (size_t)E_DIM * E_DIM;           // [4096][3072]
    __bf16* attnb = qkv + (size_t)M_ROWS * QKV_N;          // [4096][2048]

    k_convert<<<(M_ROWS * E_DIM / 4 + 255) / 256, 256, 0, stream>>>(x, xb, M_ROWS * E_DIM);
    dim3 tb(32, 8);
    k_transpose<<<dim3(E_DIM / 32, E_DIM / 32), tb, 0, stream>>>(Wq, WtAll, E_DIM, E_DIM, QK_SCALE);
    k_transpose<<<dim3(KV_DIM / 32, E_DIM / 32), tb, 0, stream>>>(Wk, WtAll + (size_t)E_DIM * E_DIM, E_DIM, KV_DIM, 1.0f);
    k_transpose<<<dim3(KV_DIM / 32, E_DIM / 32), tb, 0, stream>>>(Wv, WtAll + (size_t)(E_DIM + KV_DIM) * E_DIM, E_DIM, KV_DIM, 1.0f);
    k_transpose<<<dim3(E_DIM / 32, E_DIM / 32), tb, 0, stream>>>(Wo, WoT, E_DIM, E_DIM, 1.0f);

    k_gemm_bt<0><<<dim3(QKV_N / 128, M_ROWS / 128), 256, 0, stream>>>(
        xb, WtAll, (void*)qkv, nullptr, M_ROWS, QKV_N, E_DIM);

    k_attn<<<dim3(S_LEN / 64, 16, 2), 256, 0, stream>>>(qkv, attnb);

    k_gemm_bt<1><<<dim3(E_DIM / 128, M_ROWS / 128), 256, 0, stream>>>(
        attnb, WoT, d_out, bo, M_ROWS, E_DIM, E_DIM);
}

// Round 4
// 416.575 us; speedup vs baseline: 1.5235x; 1.1375x over previous
//
#include <hip/hip_runtime.h>
#include <hip/hip_fp16.h>

#define E_DIM 2048
#define S_LEN 2048
#define NH 32
#define HD 64
#define KV_DIM 512
#define QKV_N 3072      // E + 2*KV
#define M_ROWS 4096     // B*S
#define QK_SCALE 0.18033688011112042f  // (1/sqrt(64)) * log2(e)

typedef __bf16 bf16x8 __attribute__((ext_vector_type(8)));
typedef float f32x4 __attribute__((ext_vector_type(4)));

__device__ __forceinline__ void async_lds16(const __bf16* g, __bf16* l) {
    __builtin_amdgcn_global_load_lds(
        (const __attribute__((address_space(1))) void*)g,
        (__attribute__((address_space(3))) void*)l, 16, 0, 0);
}

// ---------------- fp32 -> bf16 elementwise convert ----------------
__global__ void k_convert(const float* __restrict__ x, __bf16* __restrict__ xb, int n) {
    int i = (blockIdx.x * blockDim.x + threadIdx.x) * 4;
    if (i < n) {
        float4 v = *(const float4*)(x + i);
        xb[i + 0] = (__bf16)v.x;
        xb[i + 1] = (__bf16)v.y;
        xb[i + 2] = (__bf16)v.z;
        xb[i + 3] = (__bf16)v.w;
    }
}

// ---------------- W[K][N] fp32 -> Wt[N][K] bf16 (transpose+convert+scale) ----------------
__global__ void k_transpose(const float* __restrict__ W, __bf16* __restrict__ Wt, int K, int N,
                            float scale) {
    __shared__ float tile[32][33];
    int n0 = blockIdx.x * 32, k0 = blockIdx.y * 32;
    int tx = threadIdx.x, ty = threadIdx.y;
#pragma unroll
    for (int j = 0; j < 4; ++j)
        tile[ty + j * 8][tx] = W[(size_t)(k0 + ty + j * 8) * N + n0 + tx];
    __syncthreads();
#pragma unroll
    for (int j = 0; j < 4; ++j)
        Wt[(size_t)(n0 + ty + j * 8) * K + k0 + tx] = (__bf16)(tile[tx][ty + j * 8] * scale);
}

// ---------------- bf16 MFMA GEMM, BK=64 per barrier round ----------------
template <int OUT_F32>
__global__ __launch_bounds__(256, 2)
void k_gemm_bt(const __bf16* __restrict__ A, const __bf16* __restrict__ Bt,
               void* __restrict__ Cout, const float* __restrict__ bias,
               int M, int N, int K) {
    __shared__ __attribute__((aligned(16))) __bf16 As[128 * 64];
    __shared__ __attribute__((aligned(16))) __bf16 Bs[128 * 64];
    const int t = threadIdx.x;
    const int lane = t & 63, wave = t >> 6;
    const int quad = lane >> 4, l16 = lane & 15;
    const int wr = wave >> 1, wc = wave & 1;
    const int m0 = blockIdx.y * 128, n0 = blockIdx.x * 128;

    const int srow = t >> 2;
    const int sblk = (t & 3) ^ ((t >> 3) & 3);
    const __bf16* gA0 = A + (size_t)(m0 + srow) * K + sblk * 8;
    const __bf16* gA1 = gA0 + (size_t)64 * K;
    const __bf16* gB0 = Bt + (size_t)(n0 + srow) * K + sblk * 8;
    const __bf16* gB1 = gB0 + (size_t)64 * K;

    f32x4 acc[4][4] = {};

    for (int k0 = 0; k0 < K; k0 += 64) {
#pragma unroll
        for (int ks = 0; ks < 2; ++ks) {
            async_lds16(gA0 + k0 + ks * 32, As + ks * 4096 + wave * 512);
            async_lds16(gA1 + k0 + ks * 32, As + ks * 4096 + 2048 + wave * 512);
            async_lds16(gB0 + k0 + ks * 32, Bs + ks * 4096 + wave * 512);
            async_lds16(gB1 + k0 + ks * 32, Bs + ks * 4096 + 2048 + wave * 512);
        }
        __syncthreads();
#pragma unroll
        for (int ks = 0; ks < 2; ++ks) {
            bf16x8 af[4], bfr[4];
#pragma unroll
            for (int i = 0; i < 4; ++i) {
                const int row = wr * 64 + i * 16 + l16;
                af[i] = *(const bf16x8*)((const char*)As + ks * 8192 + row * 64 +
                                         ((quad ^ ((row >> 1) & 3)) * 16));
            }
#pragma unroll
            for (int j = 0; j < 4; ++j) {
                const int row = wc * 64 + j * 16 + l16;
                bfr[j] = *(const bf16x8*)((const char*)Bs + ks * 8192 + row * 64 +
                                          ((quad ^ ((row >> 1) & 3)) * 16));
            }
#pragma unroll
            for (int i = 0; i < 4; ++i)
#pragma unroll
                for (int j = 0; j < 4; ++j)
                    acc[i][j] = __builtin_amdgcn_mfma_f32_16x16x32_bf16(af[i], bfr[j], acc[i][j], 0, 0, 0);
        }
        __syncthreads();
    }

#pragma unroll
    for (int i = 0; i < 4; ++i)
#pragma unroll
        for (int j = 0; j < 4; ++j) {
            const int row = m0 + wr * 64 + i * 16 + quad * 4;
            const int col = n0 + wc * 64 + j * 16 + l16;
#pragma unroll
            for (int r = 0; r < 4; ++r) {
                float v = acc[i][j][r];
                if (OUT_F32) ((float*)Cout)[(size_t)(row + r) * N + col] = v + bias[col];
                else ((__bf16*)Cout)[(size_t)(row + r) * N + col] = (__bf16)v;
            }
        }
}

// ---------------- KV-split flash attention: one block = (q-tile, 512-key chunk) ----------
// grid (80, 16 head-pairs, B). Per (b,gp): 80 chunk-blocks covering 32 q-tiles with
// ceil((qi+1)/8) chunks each. Block writes unnormalized partial O (fp16) + (m,l).
__global__ __launch_bounds__(256, 4)
void k_attn(const __bf16* __restrict__ qkv, __half* __restrict__ partO,
            float2* __restrict__ partML) {
    const int xr = (int)(gridDim.x - 1 - blockIdx.x);   // reversed: biggest q-tiles first
    int qi, c;
    if (xr < 8)       { qi = xr;                  c = 0; }
    else if (xr < 24) { qi = 8 + ((xr - 8) >> 1); c = (xr - 8) & 1; }
    else if (xr < 48) { qi = 16 + (xr - 24) / 3;  c = (xr - 24) % 3; }
    else              { qi = 24 + ((xr - 48) >> 2); c = (xr - 48) & 3; }
    const int q0 = qi * 64;
    const int k_lo = c * 512;
    const int k_hi = min(k_lo + 512, q0 + 64);

    const int gp = blockIdx.y;
    const int g = gp >> 1;
    const int h0 = g * 4 + (gp & 1) * 2;
    const int b = blockIdx.z;
    const int t = threadIdx.x;
    const int lane = t & 63, wave = t >> 6;
    const int quad = lane >> 4, l16 = lane & 15;

    __shared__ __attribute__((aligned(16))) __bf16 vT[64][136];
    __shared__ __attribute__((aligned(16))) __bf16 pT[4][2][1024];

    const __bf16* base = qkv + (size_t)b * S_LEN * QKV_N;
    const int qrow = q0 + wave * 16 + l16;

    bf16x8 qf[2][2];
#pragma unroll
    for (int h = 0; h < 2; ++h)
#pragma unroll
        for (int s = 0; s < 2; ++s)
            qf[h][s] = *(const bf16x8*)(base + (size_t)qrow * QKV_N + (h0 + h) * HD + s * 32 + quad * 8);

    f32x4 o[2][4] = {};
    float m_st[2], l_st[2];
    m_st[0] = m_st[1] = -__builtin_inff();
    l_st[0] = l_st[1] = 0.f;

    const int vkey = lane * 2, vdg = wave * 16;
    const __bf16* vsrc = base + (E_DIM + KV_DIM) + g * HD + vdg;
    const __bf16* ksrc = base + E_DIM + g * HD;

    auto qk = [&](int kb, f32x4* sA, f32x4* sB) {
#pragma unroll
        for (int kt = 0; kt < 4; ++kt) {
            const __bf16* kp = ksrc + (size_t)(kb + kt * 16 + l16) * QKV_N;
            bf16x8 kf0 = *(const bf16x8*)(kp + quad * 8);
            bf16x8 kf1 = *(const bf16x8*)(kp + 32 + quad * 8);
            f32x4 z = {};
            z = __builtin_amdgcn_mfma_f32_16x16x32_bf16(kf0, qf[0][0], z, 0, 0, 0);
            sA[kt] = __builtin_amdgcn_mfma_f32_16x16x32_bf16(kf1, qf[0][1], z, 0, 0, 0);
            f32x4 w = {};
            w = __builtin_amdgcn_mfma_f32_16x16x32_bf16(kf0, qf[1][0], w, 0, 0, 0);
            sB[kt] = __builtin_amdgcn_mfma_f32_16x16x32_bf16(kf1, qf[1][1], w, 0, 0, 0);
        }
    };

    auto softmax_p = [&](int kb, int h, f32x4* sc) {
        if (kb == q0) {  // diagonal micro tile
#pragma unroll
            for (int kt = 0; kt < 4; ++kt) {
                const int kbase = kb + kt * 16 + quad * 4;
#pragma unroll
                for (int r = 0; r < 4; ++r)
                    if (kbase + r > qrow) sc[kt][r] = -__builtin_inff();
            }
        }
        f32x4 m4;
#pragma unroll
        for (int r = 0; r < 4; ++r)
            m4[r] = fmaxf(fmaxf(sc[0][r], sc[1][r]), fmaxf(sc[2][r], sc[3][r]));
        float mx = fmaxf(fmaxf(m4[0], m4[1]), fmaxf(m4[2], m4[3]));
        mx = fmaxf(mx, __shfl_xor(mx, 16));
        mx = fmaxf(mx, __shfl_xor(mx, 32));
        const float mn = fmaxf(m_st[h], mx);
        const float al = exp2f(m_st[h] - mn);
#pragma unroll
        for (int kt = 0; kt < 4; ++kt)
#pragma unroll
            for (int r = 0; r < 4; ++r) sc[kt][r] = exp2f(sc[kt][r] - mn);
        f32x4 s4;
#pragma unroll
        for (int r = 0; r < 4; ++r)
            s4[r] = (sc[0][r] + sc[1][r]) + (sc[2][r] + sc[3][r]);
        float rs = (s4[0] + s4[1]) + (s4[2] + s4[3]);
        rs += __shfl_xor(rs, 16);
        rs += __shfl_xor(rs, 32);
        m_st[h] = mn;
        l_st[h] = l_st[h] * al + rs;
#pragma unroll
        for (int cc = 0; cc < 4; ++cc)
#pragma unroll
            for (int r = 0; r < 4; ++r) o[h][cc][r] *= al;
        char* prow = (char*)&pT[wave][h][0] + l16 * 128;
#pragma unroll
        for (int kt = 0; kt < 4; ++kt) {
            __bf16 pb[4];
#pragma unroll
            for (int r = 0; r < 4; ++r) pb[r] = (__bf16)sc[kt][r];
            *(uint2*)(prow + ((2 * kt + (quad >> 1)) ^ (l16 & 7)) * 16 + (quad & 1) * 8) =
                *(const uint2*)pb;
        }
    };

    auto pv = [&](int m) {
        bf16x8 vf[4][2];
        const int koff = m * 64;
#pragma unroll
        for (int cc = 0; cc < 4; ++cc)
#pragma unroll
            for (int kh = 0; kh < 2; ++kh)
                vf[cc][kh] = *(const bf16x8*)&vT[cc * 16 + l16][koff + kh * 32 + quad * 8];
#pragma unroll
        for (int h = 0; h < 2; ++h) {
            const char* prow = (const char*)&pT[wave][h][0] + l16 * 128;
            bf16x8 pf0 = *(const bf16x8*)(prow + ((0 + quad) ^ (l16 & 7)) * 16);
            bf16x8 pf1 = *(const bf16x8*)(prow + ((4 + quad) ^ (l16 & 7)) * 16);
#pragma unroll
            for (int cc = 0; cc < 4; ++cc) {
                o[h][cc] = __builtin_amdgcn_mfma_f32_16x16x32_bf16(vf[cc][0], pf0, o[h][cc], 0, 0, 0);
                o[h][cc] = __builtin_amdgcn_mfma_f32_16x16x32_bf16(vf[cc][1], pf1, o[h][cc], 0, 0, 0);
            }
        }
    };

    for (int kv0 = k_lo; kv0 < k_hi; kv0 += 128) {
        const __bf16* vp = vsrc + (size_t)(kv0 + vkey) * QKV_N;
        uint4 va0 = *(const uint4*)(vp);
        uint4 va1 = *(const uint4*)(vp + 8);
        uint4 vb0 = *(const uint4*)(vp + QKV_N);
        uint4 vb1 = *(const uint4*)(vp + QKV_N + 8);

        f32x4 scA[4], scB[4];
        qk(kv0, scA, scB);

        {   // pack V^T into LDS (2 keys per u32)
            const unsigned short* a0 = (const unsigned short*)&va0;
            const unsigned short* a1 = (const unsigned short*)&va1;
            const unsigned short* b0 = (const unsigned short*)&vb0;
            const unsigned short* b1 = (const unsigned short*)&vb1;
#pragma unroll
            for (int j = 0; j < 8; ++j) {
                *(uint32_t*)&vT[vdg + j][vkey] = (uint32_t)a0[j] | ((uint32_t)b0[j] << 16);
                *(uint32_t*)&vT[vdg + 8 + j][vkey] = (uint32_t)a1[j] | ((uint32_t)b1[j] << 16);
            }
        }
        softmax_p(kv0, 0, scA);
        softmax_p(kv0, 1, scB);
        __syncthreads();          // vT staged & visible
        pv(0);

        const int kb1 = kv0 + 64;
        if (kb1 < k_hi) {
            qk(kb1, scA, scB);
            softmax_p(kb1, 0, scA);
            softmax_p(kb1, 1, scB);
            pv(1);
        }
        __syncthreads();          // all vT reads done before next macro's staging
    }

    // ---- write unnormalized partial O (fp16) + (m,l) ----
    const size_t blk = ((size_t)b * 16 + gp) * 80 + xr;
    const size_t pb = blk * (2 * 64 * 64);
#pragma unroll
    for (int h = 0; h < 2; ++h) {
        __half* prow = partO + pb + (size_t)(h * 64 + wave * 16 + l16) * 64 + quad * 4;
#pragma unroll
        for (int dt = 0; dt < 4; ++dt) {
            __half ob[4];
#pragma unroll
            for (int r = 0; r < 4; ++r) ob[r] = __float2half(o[h][dt][r]);
            *(uint2*)(prow + dt * 16) = *(const uint2*)ob;
        }
        if (quad == 0)
            partML[blk * 128 + h * 64 + wave * 16 + l16] = make_float2(m_st[h], l_st[h]);
    }
}

// ---------------- combine partial chunks -> attnb (bf16) ----------------
// grid (32, 16, 2), block 256. Thread: (head,query) row + 32-d half.
__global__ __launch_bounds__(256, 4)
void k_combine(const __half* __restrict__ partO, const float2* __restrict__ partML,
               __bf16* __restrict__ attnb) {
    const int qi = blockIdx.x, gp = blockIdx.y, b = blockIdx.z;
    const int nc = (qi >> 3) + 1;
    int x0;
    if (qi < 8) x0 = qi;
    else if (qi < 16) x0 = 8 + (qi - 8) * 2;
    else if (qi < 24) x0 = 24 + (qi - 16) * 3;
    else x0 = 48 + (qi - 24) * 4;

    const int t = threadIdx.x;
    const int row = t >> 1, half = t & 1;
    const int h = row >> 6, q = row & 63;
    const int d0 = half * 32;
    const size_t gbase = ((size_t)b * 16 + gp) * 80;

    float M = -__builtin_inff();
    float2 ml[4];
    for (int cc = 0; cc < nc; ++cc) {
        ml[cc] = partML[(gbase + x0 + cc) * 128 + h * 64 + q];
        M = fmaxf(M, ml[cc].x);
    }
    float W = 0.f;
    float acc[32];
#pragma unroll
    for (int i = 0; i < 32; ++i) acc[i] = 0.f;
    for (int cc = 0; cc < nc; ++cc) {
        const float a = exp2f(ml[cc].x - M);
        W += a * ml[cc].y;
        const __half* src = partO + (gbase + x0 + cc) * (2 * 64 * 64) + (size_t)(h * 64 + q) * 64 + d0;
#pragma unroll
        for (int i = 0; i < 32; i += 8) {
            uint4 u = *(const uint4*)(src + i);
            const __half* hs = (const __half*)&u;
#pragma unroll
            for (int j = 0; j < 8; ++j) acc[i + j] += a * __half2float(hs[j]);
        }
    }
    const float inv = 1.f / W;
    const int h_abs = (gp >> 1) * 4 + (gp & 1) * 2 + h;
    __bf16* dst = attnb + ((size_t)b * S_LEN + qi * 64 + q) * E_DIM + h_abs * 64 + d0;
#pragma unroll
    for (int i = 0; i < 32; i += 8) {
        __bf16 ob[8];
#pragma unroll
        for (int j = 0; j < 8; ++j) ob[j] = (__bf16)(acc[i + j] * inv);
        *(uint4*)(dst + i) = *(const uint4*)ob;
    }
}

// ---------------- launch ----------------
extern "C" void kernel_launch(void* const* d_in, const int* in_sizes, int n_in,
                              void* d_out, int out_size, void* d_ws, size_t ws_size,
                              hipStream_t stream) {
    const float* x  = (const float*)d_in[0];
    const float* Wq = (const float*)d_in[1];
    const float* Wk = (const float*)d_in[2];
    const float* Wv = (const float*)d_in[3];
    const float* Wo = (const float*)d_in[4];
    const float* bo = (const float*)d_in[5];

    __bf16* xb    = (__bf16*)d_ws;                         // [4096][2048]
    __bf16* WtAll = xb + (size_t)M_ROWS * E_DIM;           // [3072][2048]
    __bf16* WoT   = WtAll + (size_t)QKV_N * E_DIM;         // [2048][2048]
    __bf16* qkv   = WoT + (size_t)E_DIM * E_DIM;           // [4096][3072]
    __bf16* attnb = qkv + (size_t)M_ROWS * QKV_N;          // [4096][2048]
    __half* partO = (__half*)(attnb + (size_t)M_ROWS * E_DIM);   // [2*16*80][2*64*64]
    float2* partML = (float2*)(partO + (size_t)2 * 16 * 80 * 2 * 64 * 64);  // [2*16*80][128]

    k_convert<<<(M_ROWS * E_DIM / 4 + 255) / 256, 256, 0, stream>>>(x, xb, M_ROWS * E_DIM);
    dim3 tb(32, 8);
    k_transpose<<<dim3(E_DIM / 32, E_DIM / 32), tb, 0, stream>>>(Wq, WtAll, E_DIM, E_DIM, QK_SCALE);
    k_transpose<<<dim3(KV_DIM / 32, E_DIM / 32), tb, 0, stream>>>(Wk, WtAll + (size_t)E_DIM * E_DIM, E_DIM, KV_DIM, 1.0f);
    k_transpose<<<dim3(KV_DIM / 32, E_DIM / 32), tb, 0, stream>>>(Wv, WtAll + (size_t)(E_DIM + KV_DIM) * E_DIM, E_DIM, KV_DIM, 1.0f);
    k_transpose<<<dim3(E_DIM / 32, E_DIM / 32), tb, 0, stream>>>(Wo, WoT, E_DIM, E_DIM, 1.0f);

    k_gemm_bt<0><<<dim3(QKV_N / 128, M_ROWS / 128), 256, 0, stream>>>(
        xb, WtAll, (void*)qkv, nullptr, M_ROWS, QKV_N, E_DIM);

    k_attn<<<dim3(80, 16, 2), 256, 0, stream>>>(qkv, partO, partML);
    k_combine<<<dim3(32, 16, 2), 256, 0, stream>>>(partO, partML, attnb);

    k_gemm_bt<1><<<dim3(E_DIM / 128, M_ROWS / 128), 256, 0, stream>>>(
        attnb, WoT, d_out, bo, M_ROWS, E_DIM, E_DIM);
}